// Round 7
// baseline (778.076 us; speedup 1.0000x reference)
//
#include <hip/hip_runtime.h>
#include <cstdint>

typedef unsigned short u16;
typedef uint32_t u32;
typedef __bf16 bf16x8 __attribute__((ext_vector_type(8)));
typedef float f32x4 __attribute__((ext_vector_type(4)));

#define NB 512  // persistent blocks: exactly 2 per CU, guaranteed co-resident

__device__ __forceinline__ u16 f2bf(float f) {
  unsigned u = __float_as_uint(f);
  u += 0x7fffu + ((u >> 16) & 1u);
  return (u16)(u >> 16);
}

__device__ __forceinline__ void async16(const void* g, void* l) {
  __builtin_amdgcn_global_load_lds(
      (const __attribute__((address_space(1))) uint32_t*)g,
      (__attribute__((address_space(3))) uint32_t*)l, 16, 0, 0);
}

// device-scope grid barrier (all NB blocks co-resident by construction)
__device__ __forceinline__ void gbarrier(u32* c) {
  __syncthreads();
  __threadfence();  // release: publish this block's writes device-wide
  if (threadIdx.x == 0) {
    __hip_atomic_fetch_add(c, 1u, __ATOMIC_ACQ_REL, __HIP_MEMORY_SCOPE_AGENT);
    while (__hip_atomic_load(c, __ATOMIC_ACQUIRE, __HIP_MEMORY_SCOPE_AGENT) < NB)
      __builtin_amdgcn_s_sleep(1);
  }
  __syncthreads();
  __threadfence();  // acquire: invalidate stale lines before reading producer data
}

// ----- GEMM core: C[M,N] = A[M,K]*Bt[N,K]^T, TM x BN tile, BK=64, swizzled LDS
// MODE 0: +bias[col], cols<1024 *1/32, bf16 | MODE 1: mask+exp, bf16
// MODE 2: ones-MFMA rowsum, v/rowsum+bias, fp32 | MODE 3: transposed bf16 store
template <int MODE, int TM, int BN>
__device__ __forceinline__ void gemm_core(
    u16* As, u16* Bs,
    const u16* __restrict__ A, long lda, long bsA,
    const u16* __restrict__ Bt, long ldb, long bsB,
    void* __restrict__ C, long ldc, long bsC,
    int M, int N, int K,
    const float* __restrict__ bias, const u32* __restrict__ mbits,
    int b, int bx, int by) {
  constexpr int MT = TM / 32, NT = BN / 32;
  constexpr int ACALLS = TM / 8, TOT = (TM + BN) / 8, NC = TOT / 4;
  const int m0 = by * TM, n0 = bx * BN;
  const int lane = threadIdx.x & 63;
  const int w = threadIdx.x >> 6;
  const int wr = w >> 1, wc = w & 1;

  const int srow = lane >> 3;
  const int scol = ((lane & 7) ^ ((lane >> 3) & 7)) * 8;
  const u16* pa = A + (size_t)b * bsA + (size_t)(m0 + srow) * lda + scol;
  const u16* pb = Bt + (size_t)b * bsB + (size_t)(n0 + srow) * ldb + scol;

  const int m_l = lane & 15, q = lane >> 4, m7 = m_l & 7;
  const int offs[2] = {(q ^ m7) * 8, ((4 + q) ^ m7) * 8};

  f32x4 acc[MT][NT] = {};
  f32x4 accs[MT] = {};
  bf16x8 ones;
#pragma unroll
  for (int e = 0; e < 8; ++e) ones[e] = (__bf16)1.0f;

  for (int kt = 0; kt < K; kt += 64) {
    __syncthreads();
#pragma unroll
    for (int g = 0; g < NC; ++g) {
      const int idx = w * NC + g;
      if (idx < ACALLS)
        async16(pa + (size_t)(idx * 8) * lda, As + idx * 512);
      else
        async16(pb + (size_t)((idx - ACALLS) * 8) * ldb, Bs + (idx - ACALLS) * 512);
    }
    __syncthreads();
#pragma unroll
    for (int s = 0; s < 2; ++s) {
      bf16x8 af[MT], bfr[NT];
#pragma unroll
      for (int t = 0; t < MT; ++t)
        af[t] = *(const bf16x8*)(As + (wr * (TM / 2) + t * 16 + m_l) * 64 + offs[s]);
#pragma unroll
      for (int t = 0; t < NT; ++t)
        bfr[t] = *(const bf16x8*)(Bs + (wc * (BN / 2) + t * 16 + m_l) * 64 + offs[s]);
#pragma unroll
      for (int mt = 0; mt < MT; ++mt)
#pragma unroll
        for (int nt = 0; nt < NT; ++nt)
          acc[mt][nt] = __builtin_amdgcn_mfma_f32_16x16x32_bf16(af[mt], bfr[nt], acc[mt][nt], 0, 0, 0);
      if constexpr (MODE == 2) {
#pragma unroll
        for (int mt = 0; mt < MT; ++mt)
          accs[mt] = __builtin_amdgcn_mfma_f32_16x16x32_bf16(af[mt], ones, accs[mt], 0, 0, 0);
      }
    }
    pa += 64;
    pb += 64;
  }

  if constexpr (MODE == 1) {
    __syncthreads();
    const int rl = threadIdx.x >> 1, pr = threadIdx.x & 1;
    const uint2 v = *(const uint2*)(mbits + ((size_t)(b * M + m0 + rl)) * (N >> 5) + (n0 >> 5) + pr * 2);
    ((u32*)As)[rl * 4 + pr * 2] = v.x;
    ((u32*)As)[rl * 4 + pr * 2 + 1] = v.y;
    __syncthreads();
  }

  float rinv[MT][4];
  if constexpr (MODE == 2) {
#pragma unroll
    for (int mt = 0; mt < MT; ++mt)
#pragma unroll
      for (int r = 0; r < 4; ++r) rinv[mt][r] = 1.0f / accs[mt][r];
  }

#pragma unroll
  for (int mt = 0; mt < MT; ++mt) {
#pragma unroll
    for (int nt = 0; nt < NT; ++nt) {
      const int col = n0 + wc * (BN / 2) + nt * 16 + m_l;
      const int row0 = m0 + wr * (TM / 2) + mt * 16 + q * 4;
      if constexpr (MODE == 3) {
        ushort4 o;
        o.x = f2bf(acc[mt][nt][0]); o.y = f2bf(acc[mt][nt][1]);
        o.z = f2bf(acc[mt][nt][2]); o.w = f2bf(acc[mt][nt][3]);
        *(ushort4*)((u16*)C + (size_t)b * bsC + (size_t)col * ldc + row0) = o;
      } else {
#pragma unroll
        for (int r = 0; r < 4; ++r) {
          const int row = row0 + r;
          float v = acc[mt][nt][r];
          if constexpr (MODE == 0) {
            v += bias[col];
            if (col < 1024) v *= 0.03125f;
            ((u16*)C)[(size_t)b * bsC + (size_t)row * ldc + col] = f2bf(v);
          } else if constexpr (MODE == 1) {
            const int cl = wc * 64 + nt * 16 + m_l;
            const int rl = wr * 64 + mt * 16 + q * 4 + r;
            const u32 wb = ((const u32*)As)[rl * 4 + (cl >> 5)];
            v = ((wb >> (cl & 31)) & 1u) ? __expf(fminf(v, 30.f)) : 0.f;
            ((u16*)C)[(size_t)b * bsC + (size_t)row * ldc + col] = f2bf(v);
          } else if constexpr (MODE == 2) {
            v = v * rinv[mt][r] + bias[col];
            ((float*)C)[(size_t)b * bsC + (size_t)row * ldc + col] = v;
          }
        }
      }
    }
  }
}

// ---------------- persistent mega-kernel: all phases, 3 grid barriers ----------
__global__ __launch_bounds__(256, 2) void k_mega(
    const float* __restrict__ x, const int* __restrict__ mask,
    const float* __restrict__ pw, const float* __restrict__ pb,
    const float* __restrict__ ow, const float* __restrict__ ob,
    float* __restrict__ out, char* __restrict__ ws) {
  __shared__ u16 As[128 * 64];
  __shared__ u16 Bs[128 * 64];
  u16* xb = (u16*)(ws);                      // 16.8 MB; Ut aliases after qkv phase
  u16* wt = (u16*)(ws + 16777216);           // 6.3 MB
  u16* owt = (u16*)(ws + 23068672);          // 2.1 MB
  u16* qkv = (u16*)(ws + 25165824);          // 50.3 MB
  u16* P = (u16*)(ws + 75497472);            // 33.6 MB
  u32* mbits = (u32*)(ws + 109051904);       // 2.1 MB
  u32* cnt = (u32*)(ws + 111149056);         // [0]=ready flag, [1..3]=barriers
  u16* Ut = xb;
  const int bid = blockIdx.x;

  // --- init handshake: block 0 zeroes barrier counters, sets magic flag ---
  if (bid == 0 && threadIdx.x == 0) {
    __hip_atomic_store(&cnt[1], 0u, __ATOMIC_RELAXED, __HIP_MEMORY_SCOPE_AGENT);
    __hip_atomic_store(&cnt[2], 0u, __ATOMIC_RELAXED, __HIP_MEMORY_SCOPE_AGENT);
    __hip_atomic_store(&cnt[3], 0u, __ATOMIC_RELAXED, __HIP_MEMORY_SCOPE_AGENT);
    __hip_atomic_store(&cnt[0], 0xC0FFEEu, __ATOMIC_RELEASE, __HIP_MEMORY_SCOPE_AGENT);
  }
  if (threadIdx.x == 0) {
    while (__hip_atomic_load(&cnt[0], __ATOMIC_ACQUIRE, __HIP_MEMORY_SCOPE_AGENT) != 0xC0FFEEu)
      __builtin_amdgcn_s_sleep(1);
  }
  __syncthreads();

  // ---- phase 0: prep (28 units/block) ----
  for (int u = bid; u < 14336; u += NB) {
    if (u < 8192) {  // x -> bf16
      const int i = u * 256 + threadIdx.x;
      const float4 v = ((const float4*)x)[i];
      ushort4 o;
      o.x = f2bf(v.x); o.y = f2bf(v.y); o.z = f2bf(v.z); o.w = f2bf(v.w);
      ((ushort4*)xb)[i] = o;
    } else if (u >= 12288) {  // mask bitpack
      const size_t wd = (size_t)(u - 12288) * 256 + threadIdx.x;
      const int* p = mask + wd * 32;
      u32 bits = 0;
#pragma unroll
      for (int j = 0; j < 8; ++j) {
        const int4 v = ((const int4*)p)[j];
        bits |= (u32)(v.x & 1) << (j * 4 + 0);
        bits |= (u32)(v.y & 1) << (j * 4 + 1);
        bits |= (u32)(v.z & 1) << (j * 4 + 2);
        bits |= (u32)(v.w & 1) << (j * 4 + 3);
      }
      mbits[wd] = bits;
    } else {  // weight transposes (LDS tile carved from As)
      u16(*tile)[33] = (u16(*)[33])As;
      const int tx = threadIdx.x & 31, ty = threadIdx.x >> 5;
      const float* in;
      u16* outp;
      int lda, ldo, c0, r0;
      if (u < 11264) {
        const int id = u - 8192;  // proj_w [1024][3072] -> wt [3072][1024]
        c0 = (id % 96) * 32; r0 = (id / 96) * 32;
        in = pw; outp = wt; lda = 3072; ldo = 1024;
      } else {
        const int id = u - 11264;  // out_w -> owt
        c0 = (id % 32) * 32; r0 = (id / 32) * 32;
        in = ow; outp = owt; lda = 1024; ldo = 1024;
      }
#pragma unroll
      for (int i = 0; i < 4; ++i)
        tile[ty + i * 8][tx] = f2bf(in[(size_t)(r0 + ty + i * 8) * lda + c0 + tx]);
      __syncthreads();
#pragma unroll
      for (int i = 0; i < 4; ++i)
        outp[(size_t)(c0 + ty + i * 8) * ldo + r0 + tx] = tile[tx][ty + i * 8];
      __syncthreads();  // WAR before tile reuse next unit
    }
  }
  gbarrier(&cnt[1]);

  // ---- phase 1: qkv = x @ proj_w + b (q prescaled 1/32), 3 tiles/block ----
  for (int t = bid; t < 1536; t += NB)
    gemm_core<0, 128, 128>(As, Bs, xb, 1024, 0, wt, 1024, 0, qkv, 3072, 0,
                           8192, 3072, 1024, pb, nullptr, 0, t % 24, t / 24);
  gbarrier(&cnt[2]);

  // ---- phase 2: score tiles first (all blocks), then VW tiles ----
  for (int t = bid; t < 2048; t += NB) {
    if (t < 1024) {  // P = mask ? exp(q k^T /32) : 0
      gemm_core<1, 128, 128>(As, Bs,
          qkv, 3072, (long)2048 * 3072, qkv + 1024, 3072, (long)2048 * 3072,
          P, 2048, (long)2048 * 2048, 2048, 2048, 1024, nullptr, mbits,
          t >> 8, t & 15, (t >> 4) & 15);
    } else {  // Ut = (V @ out_w)^T
      const int t2 = t - 1024;
      gemm_core<3, 64, 128>(As, Bs,
          qkv + 2048, 3072, (long)2048 * 3072, owt, 1024, 0,
          Ut, 2048, (long)1024 * 2048, 2048, 1024, 1024, nullptr, nullptr,
          t2 >> 8, t2 & 7, (t2 >> 3) & 31);
    }
  }
  gbarrier(&cnt[3]);

  // ---- phase 3: out = P @ U / rowsum(P) + out_b, 2 tiles/block ----
  for (int t = bid; t < 1024; t += NB)
    gemm_core<2, 64, 128>(As, Bs,
        P, 2048, (long)2048 * 2048, Ut, 2048, (long)1024 * 2048,
        out, 1024, (long)2048 * 1024, 2048, 1024, 2048, ob, nullptr,
        t >> 8, t & 7, (t >> 3) & 31);
}

extern "C" void kernel_launch(void* const* d_in, const int* in_sizes, int n_in,
                              void* d_out, int out_size, void* d_ws, size_t ws_size,
                              hipStream_t stream) {
  const float* x = (const float*)d_in[0];
  const int* mask = (const int*)d_in[1];
  const float* proj_w = (const float*)d_in[2];
  const float* proj_b = (const float*)d_in[3];
  const float* out_w = (const float*)d_in[4];
  const float* out_b = (const float*)d_in[5];
  float* out = (float*)d_out;

  k_mega<<<NB, 256, 0, stream>>>(x, mask, proj_w, proj_b, out_w, out_b, out, (char*)d_ws);
}

// Round 8
// 330.074 us; speedup vs baseline: 2.3573x; 2.3573x over previous
//
#include <hip/hip_runtime.h>
#include <cstdint>

typedef unsigned short u16;
typedef uint32_t u32;
typedef __bf16 bf16x8 __attribute__((ext_vector_type(8)));
typedef float f32x4 __attribute__((ext_vector_type(4)));

__device__ __forceinline__ u16 f2bf(float f) {
  unsigned u = __float_as_uint(f);
  u += 0x7fffu + ((u >> 16) & 1u);
  return (u16)(u >> 16);
}

__device__ __forceinline__ void async16(const void* g, void* l) {
  __builtin_amdgcn_global_load_lds(
      (const __attribute__((address_space(1))) uint32_t*)g,
      (__attribute__((address_space(3))) uint32_t*)l, 16, 0, 0);
}

// --- fused prep: x->bf16 | proj_w^T | out_w^T | mask bitpack (one dispatch) ---
__global__ __launch_bounds__(256) void k_prep(const float* __restrict__ x, u16* __restrict__ xb,
                                              const float* __restrict__ pw, u16* __restrict__ wt,
                                              const float* __restrict__ ow, u16* __restrict__ owt,
                                              const int* __restrict__ mask, u32* __restrict__ mbits) {
  const int bid = blockIdx.x;
  if (bid < 8192) {
    const int i = bid * 256 + threadIdx.x;
    const float4 v = ((const float4*)x)[i];
    ushort4 o;
    o.x = f2bf(v.x); o.y = f2bf(v.y); o.z = f2bf(v.z); o.w = f2bf(v.w);
    ((ushort4*)xb)[i] = o;
    return;
  }
  if (bid >= 12288) {
    const size_t w = (size_t)(bid - 12288) * 256 + threadIdx.x;
    const int* p = mask + w * 32;
    u32 bits = 0;
#pragma unroll
    for (int j = 0; j < 8; ++j) {
      const int4 v = ((const int4*)p)[j];
      bits |= (u32)(v.x & 1) << (j * 4 + 0);
      bits |= (u32)(v.y & 1) << (j * 4 + 1);
      bits |= (u32)(v.z & 1) << (j * 4 + 2);
      bits |= (u32)(v.w & 1) << (j * 4 + 3);
    }
    mbits[w] = bits;
    return;
  }
  __shared__ u16 tile[32][33];
  const int tx = threadIdx.x & 31, ty = threadIdx.x >> 5;
  const float* in;
  u16* outp;
  int lda, ldo, c0, r0;
  if (bid < 11264) {
    const int id = bid - 8192;  // proj_w [1024][3072] -> wt [3072][1024]
    c0 = (id % 96) * 32; r0 = (id / 96) * 32;
    in = pw; outp = wt; lda = 3072; ldo = 1024;
  } else {
    const int id = bid - 11264;  // out_w [1024][1024] -> owt
    c0 = (id % 32) * 32; r0 = (id / 32) * 32;
    in = ow; outp = owt; lda = 1024; ldo = 1024;
  }
#pragma unroll
  for (int i = 0; i < 4; ++i)
    tile[ty + i * 8][tx] = f2bf(in[(size_t)(r0 + ty + i * 8) * lda + c0 + tx]);
  __syncthreads();
#pragma unroll
  for (int i = 0; i < 4; ++i)
    outp[(size_t)(c0 + ty + i * 8) * ldo + r0 + tx] = tile[tx][ty + i * 8];
}

// ----- GEMM core: C[M,N] = A[M,K]*Bt[N,K]^T, TM x BN tile, BK=64, swizzled LDS
// MODE 0: +bias[col], cols<1024 *1/32, bf16 | MODE 1: mask+exp, bf16
// MODE 2: ones-MFMA rowsum, v/rowsum+bias, fp32 | MODE 3: transposed bf16 store
template <int MODE, int TM, int BN>
__device__ __forceinline__ void gemm_core(
    u16* As, u16* Bs,
    const u16* __restrict__ A, long lda, long bsA,
    const u16* __restrict__ Bt, long ldb, long bsB,
    void* __restrict__ C, long ldc, long bsC,
    int M, int N, int K,
    const float* __restrict__ bias, const u32* __restrict__ mbits,
    int b, int bx, int by) {
  constexpr int MT = TM / 32, NT = BN / 32;
  constexpr int ACALLS = TM / 8, TOT = (TM + BN) / 8, NC = TOT / 4;
  const int m0 = by * TM, n0 = bx * BN;
  const int lane = threadIdx.x & 63;
  const int w = threadIdx.x >> 6;
  const int wr = w >> 1, wc = w & 1;

  const int srow = lane >> 3;
  const int scol = ((lane & 7) ^ ((lane >> 3) & 7)) * 8;
  const u16* pa = A + (size_t)b * bsA + (size_t)(m0 + srow) * lda + scol;
  const u16* pb = Bt + (size_t)b * bsB + (size_t)(n0 + srow) * ldb + scol;

  const int m_l = lane & 15, q = lane >> 4, m7 = m_l & 7;
  const int offs[2] = {(q ^ m7) * 8, ((4 + q) ^ m7) * 8};

  f32x4 acc[MT][NT] = {};
  f32x4 accs[MT] = {};
  bf16x8 ones;
#pragma unroll
  for (int e = 0; e < 8; ++e) ones[e] = (__bf16)1.0f;

  for (int kt = 0; kt < K; kt += 64) {
    __syncthreads();
#pragma unroll
    for (int g = 0; g < NC; ++g) {
      const int idx = w * NC + g;
      if (idx < ACALLS)
        async16(pa + (size_t)(idx * 8) * lda, As + idx * 512);
      else
        async16(pb + (size_t)((idx - ACALLS) * 8) * ldb, Bs + (idx - ACALLS) * 512);
    }
    __syncthreads();
#pragma unroll
    for (int s = 0; s < 2; ++s) {
      bf16x8 af[MT], bfr[NT];
#pragma unroll
      for (int t = 0; t < MT; ++t)
        af[t] = *(const bf16x8*)(As + (wr * (TM / 2) + t * 16 + m_l) * 64 + offs[s]);
#pragma unroll
      for (int t = 0; t < NT; ++t)
        bfr[t] = *(const bf16x8*)(Bs + (wc * (BN / 2) + t * 16 + m_l) * 64 + offs[s]);
#pragma unroll
      for (int mt = 0; mt < MT; ++mt)
#pragma unroll
        for (int nt = 0; nt < NT; ++nt)
          acc[mt][nt] = __builtin_amdgcn_mfma_f32_16x16x32_bf16(af[mt], bfr[nt], acc[mt][nt], 0, 0, 0);
      if constexpr (MODE == 2) {
#pragma unroll
        for (int mt = 0; mt < MT; ++mt)
          accs[mt] = __builtin_amdgcn_mfma_f32_16x16x32_bf16(af[mt], ones, accs[mt], 0, 0, 0);
      }
    }
    pa += 64;
    pb += 64;
  }

  if constexpr (MODE == 1) {
    __syncthreads();
    const int rl = threadIdx.x >> 1, pr = threadIdx.x & 1;
    const uint2 v = *(const uint2*)(mbits + ((size_t)(b * M + m0 + rl)) * (N >> 5) + (n0 >> 5) + pr * 2);
    ((u32*)As)[rl * 4 + pr * 2] = v.x;
    ((u32*)As)[rl * 4 + pr * 2 + 1] = v.y;
    __syncthreads();
  }

  float rinv[MT][4];
  if constexpr (MODE == 2) {
#pragma unroll
    for (int mt = 0; mt < MT; ++mt)
#pragma unroll
      for (int r = 0; r < 4; ++r) rinv[mt][r] = 1.0f / accs[mt][r];
  }

#pragma unroll
  for (int mt = 0; mt < MT; ++mt) {
#pragma unroll
    for (int nt = 0; nt < NT; ++nt) {
      const int col = n0 + wc * (BN / 2) + nt * 16 + m_l;
      const int row0 = m0 + wr * (TM / 2) + mt * 16 + q * 4;
      if constexpr (MODE == 3) {
        ushort4 o;
        o.x = f2bf(acc[mt][nt][0]); o.y = f2bf(acc[mt][nt][1]);
        o.z = f2bf(acc[mt][nt][2]); o.w = f2bf(acc[mt][nt][3]);
        *(ushort4*)((u16*)C + (size_t)b * bsC + (size_t)col * ldc + row0) = o;
      } else {
#pragma unroll
        for (int r = 0; r < 4; ++r) {
          const int row = row0 + r;
          float v = acc[mt][nt][r];
          if constexpr (MODE == 0) {
            v += bias[col];
            if (col < 1024) v *= 0.03125f;
            ((u16*)C)[(size_t)b * bsC + (size_t)row * ldc + col] = f2bf(v);
          } else if constexpr (MODE == 1) {
            const int cl = wc * 64 + nt * 16 + m_l;
            const int rl = wr * 64 + mt * 16 + q * 4 + r;
            const u32 wb = ((const u32*)As)[rl * 4 + (cl >> 5)];
            v = ((wb >> (cl & 31)) & 1u) ? __expf(fminf(v, 30.f)) : 0.f;
            ((u16*)C)[(size_t)b * bsC + (size_t)row * ldc + col] = f2bf(v);
          } else if constexpr (MODE == 2) {
            v = v * rinv[mt][r] + bias[col];
            ((float*)C)[(size_t)b * bsC + (size_t)row * ldc + col] = v;
          }
        }
      }
    }
  }
}

// wrapper with XCD-aware swizzle: XCD k (= linear%8 round-robin) gets a
// contiguous chunk of tile space -> A-row-bands stay resident in its L2.
template <int MODE, int TM, int BN>
__global__ __launch_bounds__(256) void gemm_bt(
    const u16* __restrict__ A, long lda, long bsA,
    const u16* __restrict__ Bt, long ldb, long bsB,
    void* __restrict__ C, long ldc, long bsC,
    int M, int N, int K,
    const float* __restrict__ bias, const u32* __restrict__ mbits) {
  __shared__ u16 As[TM * 64];
  __shared__ u16 Bs[BN * 64];
  const int gx = gridDim.x, gxy = gridDim.x * gridDim.y;
  const int T = gxy * gridDim.z;
  int L = blockIdx.x + gx * blockIdx.y + gxy * blockIdx.z;
  L = (L & 7) * (T >> 3) + (L >> 3);  // T divisible by 8 for all our grids
  const int bz = L / gxy, r = L % gxy;
  gemm_core<MODE, TM, BN>(As, Bs, A, lda, bsA, Bt, ldb, bsB, C, ldc, bsC, M, N, K,
                          bias, mbits, bz, r % gx, r / gx);
}

extern "C" void kernel_launch(void* const* d_in, const int* in_sizes, int n_in,
                              void* d_out, int out_size, void* d_ws, size_t ws_size,
                              hipStream_t stream) {
  const float* x = (const float*)d_in[0];
  const int* mask = (const int*)d_in[1];
  const float* proj_w = (const float*)d_in[2];
  const float* proj_b = (const float*)d_in[3];
  const float* out_w = (const float*)d_in[4];
  const float* out_b = (const float*)d_in[5];
  float* out = (float*)d_out;

  char* ws = (char*)d_ws;
  u16* xb = (u16*)(ws);                      // 16.8 MB; Ut aliases after qkv
  u16* wt = (u16*)(ws + 16777216);           // 6.3 MB
  u16* owt = (u16*)(ws + 23068672);          // 2.1 MB
  u16* qkv = (u16*)(ws + 25165824);          // 50.3 MB
  u16* P = (u16*)(ws + 75497472);            // 33.6 MB
  u32* mbits = (u32*)(ws + 109051904);       // 2.1 MB
  u16* Ut = (u16*)xb;                        // 16.8 MB [4][1024][2048]

  // 1. prep
  k_prep<<<14336, 256, 0, stream>>>(x, xb, proj_w, wt, out_w, owt, mask, mbits);
  // 2. qkv = x @ proj_w + b (q prescaled 1/32)   T=1536
  gemm_bt<0, 128, 128><<<dim3(24, 64, 1), 256, 0, stream>>>(
      xb, 1024, 0, wt, 1024, 0, qkv, 3072, 0, 8192, 3072, 1024, proj_b, nullptr);
  // 3. P = mask ? exp(q k^T / 32) : 0            T=1024
  gemm_bt<1, 128, 128><<<dim3(16, 16, 4), 256, 0, stream>>>(
      qkv, 3072, (long)2048 * 3072, qkv + 1024, 3072, (long)2048 * 3072,
      P, 2048, (long)2048 * 2048, 2048, 2048, 1024, nullptr, mbits);
  // 4. Ut = (V @ out_w)^T                        T=1024
  gemm_bt<3, 64, 128><<<dim3(8, 32, 4), 256, 0, stream>>>(
      qkv + 2048, 3072, (long)2048 * 3072, owt, 1024, 0,
      Ut, 2048, (long)1024 * 2048, 2048, 1024, 1024, nullptr, nullptr);
  // 5. out = P @ U / rowsum(P) + out_b           T=512 (TM=128: half the staging)
  gemm_bt<2, 128, 128><<<dim3(8, 16, 4), 256, 0, stream>>>(
      P, 2048, (long)2048 * 2048, Ut, 2048, (long)1024 * 2048,
      out, 1024, (long)2048 * 1024, 2048, 1024, 2048, out_b, nullptr);
}